// Round 1
// baseline (767.024 us; speedup 1.0000x reference)
//
#include <hip/hip_runtime.h>
#include <hip/hip_bf16.h>

#define B_  32
#define S_  4096
#define H_  1024
#define NH_ 16
#define DK_ 64

// workspace layout (float offsets)
#define Q_OFF  0
#define T_OFF  (Q_OFF + B_*H_)            // q: B*H
#define C_OFF  (T_OFF + B_*NH_*H_)        // t: B*NH*H
#define SC_OFF (C_OFF + B_*NH_)           // c: B*NH
#define Y_OFF  (SC_OFF + B_*NH_*S_)       // scores/attn: B*NH*S
#define OP_OFF (Y_OFF + B_*NH_*H_)        // y: B*NH*H
// out_pre: B*H after OP_OFF

// ---------------- kernel 1: q[b,i] = x[b,S-1,:] . Wq[i,:] + bq[i] ----------
__global__ __launch_bounds__(256) void k_q(const float* __restrict__ x,
                                           const float* __restrict__ Wq,
                                           const float* __restrict__ bq,
                                           float* __restrict__ q) {
  __shared__ float xrow[H_];
  int b = blockIdx.y, qtr = blockIdx.x, tid = threadIdx.x;
  const float* xp = x + ((size_t)b * S_ + (S_ - 1)) * H_;
  *(float4*)&xrow[tid * 4] = *(const float4*)&xp[tid * 4];
  __syncthreads();
  int i = qtr * 256 + tid;
  const float* w = Wq + (size_t)i * H_;
  float acc = bq[i];
  #pragma unroll 4
  for (int j = 0; j < H_; j += 4) {
    float4 wv = *(const float4*)&w[j];
    acc += xrow[j] * wv.x + xrow[j + 1] * wv.y + xrow[j + 2] * wv.z + xrow[j + 3] * wv.w;
  }
  q[(size_t)b * H_ + i] = acc;
}

// -------- kernel 2: t[b,h,j] = sum_d q[b,h,d]*Wk[h*64+d, j]; c[b,h]=q.bk ---
__global__ __launch_bounds__(256) void k_t(const float* __restrict__ q,
                                           const float* __restrict__ Wk,
                                           const float* __restrict__ bk,
                                           float* __restrict__ t,
                                           float* __restrict__ c) {
  int h = blockIdx.x, b = blockIdx.y, tid = threadIdx.x;
  __shared__ float qs[DK_];
  if (tid < DK_) qs[tid] = q[(size_t)b * H_ + h * DK_ + tid];
  __syncthreads();
  if (tid < 64) {
    float p = qs[tid] * bk[h * DK_ + tid];
    #pragma unroll
    for (int o = 32; o; o >>= 1) p += __shfl_down(p, o);
    if (tid == 0) c[b * NH_ + h] = p;
  }
  for (int j = tid; j < H_; j += 256) {
    float acc = 0.f;
    #pragma unroll 8
    for (int d = 0; d < DK_; ++d)
      acc += qs[d] * Wk[((size_t)(h * DK_ + d)) * H_ + j];
    t[((size_t)(b * NH_ + h)) * H_ + j] = acc;
  }
}

// --------- kernel 3: scores[b,h,s] = (t[b,h,:].x[b,s,:] + c[b,h])*scale ----
// lane quad g=0..3 covers j-quarters; 4 rows per lane; 64 rows per wave.
__device__ __forceinline__ int sw_idx(int i) { return i ^ ((i >> 3) & 3); }

__global__ __launch_bounds__(256, 2) void k_scores(const float* __restrict__ x,
                                                   const float* __restrict__ t,
                                                   const float* __restrict__ c,
                                                   float* __restrict__ scores) {
  __shared__ float4 tp[NH_ * 64 * 4];  // 64 KB: [h][jj][g], XOR-swizzled
  int b = blockIdx.y, tid = threadIdx.x;
  const float4* t4 = (const float4*)(t + (size_t)b * NH_ * H_);
  #pragma unroll
  for (int k = 0; k < 16; ++k) {
    int f = tid + k * 256;
    float4 v = t4[f];
    int h = f >> 8;
    int g = (f >> 6) & 3;
    int jj = f & 63;
    tp[sw_idx((h * 64 + jj) * 4 + g)] = v;
  }
  __syncthreads();

  int w = tid >> 6, l = tid & 63;
  int r = l >> 2, g = l & 3;
  int sbase = blockIdx.x * 256 + w * 64;
  const float* xp0 = x + ((size_t)b * S_ + sbase + r) * H_ + g * 256;

  float acc[4][NH_];
  #pragma unroll
  for (int rr = 0; rr < 4; ++rr)
    #pragma unroll
    for (int h = 0; h < NH_; ++h) acc[rr][h] = 0.f;

  #pragma unroll 2
  for (int jj = 0; jj < 64; ++jj) {
    float4 xv[4];
    #pragma unroll
    for (int rr = 0; rr < 4; ++rr)
      xv[rr] = *(const float4*)(xp0 + (size_t)rr * 16 * H_ + jj * 4);
    #pragma unroll
    for (int h = 0; h < NH_; ++h) {
      float4 tv = tp[sw_idx((h * 64 + jj) * 4 + g)];
      #pragma unroll
      for (int rr = 0; rr < 4; ++rr)
        acc[rr][h] += xv[rr].x * tv.x + xv[rr].y * tv.y + xv[rr].z * tv.z + xv[rr].w * tv.w;
    }
  }

  #pragma unroll
  for (int rr = 0; rr < 4; ++rr) {
    #pragma unroll
    for (int h = 0; h < NH_; ++h) {
      float a = acc[rr][h];
      a += __shfl_xor(a, 1);
      a += __shfl_xor(a, 2);
      acc[rr][h] = a;
    }
  }
  #pragma unroll
  for (int rr = 0; rr < 4; ++rr) {
    int s = sbase + rr * 16 + r;
    #pragma unroll
    for (int hh = 0; hh < 4; ++hh) {
      int h = g * 4 + hh;
      scores[((size_t)(b * NH_ + h)) * S_ + s] = (acc[rr][h] + c[b * NH_ + h]) * 0.125f;
    }
  }
}

// ---------------- kernel 4: in-place softmax over S ------------------------
__global__ __launch_bounds__(256) void k_softmax(float* __restrict__ sc) {
  int h = blockIdx.x, b = blockIdx.y, tid = threadIdx.x;
  float* p = sc + ((size_t)(b * NH_ + h)) * S_;
  float4 v[4];
  float m = -3.4e38f;
  #pragma unroll
  for (int k = 0; k < 4; ++k) {
    v[k] = *(const float4*)(p + (size_t)(k * 256 + tid) * 4);
    m = fmaxf(m, fmaxf(fmaxf(v[k].x, v[k].y), fmaxf(v[k].z, v[k].w)));
  }
  __shared__ float redm[4], reds[4];
  #pragma unroll
  for (int o = 32; o; o >>= 1) m = fmaxf(m, __shfl_xor(m, o));
  if ((tid & 63) == 0) redm[tid >> 6] = m;
  __syncthreads();
  m = fmaxf(fmaxf(redm[0], redm[1]), fmaxf(redm[2], redm[3]));
  float s = 0.f;
  #pragma unroll
  for (int k = 0; k < 4; ++k) {
    v[k].x = __expf(v[k].x - m);
    v[k].y = __expf(v[k].y - m);
    v[k].z = __expf(v[k].z - m);
    v[k].w = __expf(v[k].w - m);
    s += v[k].x + v[k].y + v[k].z + v[k].w;
  }
  #pragma unroll
  for (int o = 32; o; o >>= 1) s += __shfl_xor(s, o);
  if ((tid & 63) == 0) reds[tid >> 6] = s;
  __syncthreads();
  s = reds[0] + reds[1] + reds[2] + reds[3];
  float inv = 1.f / s;
  #pragma unroll
  for (int k = 0; k < 4; ++k) {
    v[k].x *= inv; v[k].y *= inv; v[k].z *= inv; v[k].w *= inv;
    *(float4*)(p + (size_t)(k * 256 + tid) * 4) = v[k];
  }
}

// ------------ kernel 5: y[b,h,j] += sum_s attn[b,h,s]*x[b,s,j] -------------
__global__ __launch_bounds__(256) void k_y(const float* __restrict__ x,
                                           const float* __restrict__ attn,
                                           float* __restrict__ y) {
  int scid = blockIdx.x;           // s-chunk 0..7 (512 rows each)
  int jt = blockIdx.y;             // j-tile 0..3 (256 cols each)
  int b = blockIdx.z;
  int tid = threadIdx.x;
  int j = jt * 256 + tid;
  int s0 = scid * 512;
  const float* xp = x + ((size_t)b * S_ + s0) * H_ + j;
  float acc[NH_];
  #pragma unroll
  for (int h = 0; h < NH_; ++h) acc[h] = 0.f;
  for (int ss = 0; ss < 512; ss += 4) {
    float x0 = xp[(size_t)(ss + 0) * H_];
    float x1 = xp[(size_t)(ss + 1) * H_];
    float x2 = xp[(size_t)(ss + 2) * H_];
    float x3 = xp[(size_t)(ss + 3) * H_];
    #pragma unroll
    for (int h = 0; h < NH_; ++h) {
      // block-uniform address -> scalar load expected
      float4 a = *(const float4*)(attn + ((size_t)(b * NH_ + h)) * S_ + s0 + ss);
      acc[h] += a.x * x0 + a.y * x1 + a.z * x2 + a.w * x3;
    }
  }
  float* yp = y + ((size_t)(b * NH_)) * H_ + j;
  #pragma unroll
  for (int h = 0; h < NH_; ++h) atomicAdd(yp + (size_t)h * H_, acc[h]);
}

// -------- kernel 6: out_pre[b,h*64+d] = Wv[h*64+d,:].y[b,h,:] + bv ---------
__global__ __launch_bounds__(256) void k_vproj(const float* __restrict__ y,
                                               const float* __restrict__ Wv,
                                               const float* __restrict__ bv,
                                               float* __restrict__ op) {
  int h = blockIdx.x, b = blockIdx.y, tid = threadIdx.x;
  __shared__ float ys[H_];
  const float* yp = y + ((size_t)(b * NH_ + h)) * H_;
  *(float4*)&ys[tid * 4] = *(const float4*)(yp + tid * 4);
  __syncthreads();
  int d = tid >> 2, p = tid & 3;
  const float* w = Wv + ((size_t)(h * DK_ + d)) * H_ + p * 256;
  float a = 0.f;
  #pragma unroll 4
  for (int jj = 0; jj < 256; jj += 4) {
    float4 wv = *(const float4*)(w + jj);
    a += ys[p * 256 + jj] * wv.x + ys[p * 256 + jj + 1] * wv.y +
         ys[p * 256 + jj + 2] * wv.z + ys[p * 256 + jj + 3] * wv.w;
  }
  a += __shfl_xor(a, 1);
  a += __shfl_xor(a, 2);
  if (p == 0) op[(size_t)b * H_ + h * DK_ + d] = a + bv[h * DK_ + d];
}

// -------- kernel 7: out[b,i] = Wo[i,:].out_pre[b,:] + bo[i] ----------------
__global__ __launch_bounds__(256) void k_out(const float* __restrict__ op,
                                             const float* __restrict__ Wo,
                                             const float* __restrict__ bo,
                                             float* __restrict__ out) {
  int qtr = blockIdx.x, b = blockIdx.y, tid = threadIdx.x;
  __shared__ float us[H_];
  *(float4*)&us[tid * 4] = *(const float4*)(op + (size_t)b * H_ + tid * 4);
  __syncthreads();
  int i = qtr * 256 + tid;
  const float* w = Wo + (size_t)i * H_;
  float a = bo[i];
  #pragma unroll 4
  for (int jv = 0; jv < H_; jv += 4) {
    float4 wv = *(const float4*)(w + jv);
    a += us[jv] * wv.x + us[jv + 1] * wv.y + us[jv + 2] * wv.z + us[jv + 3] * wv.w;
  }
  out[(size_t)b * H_ + i] = a;
}

extern "C" void kernel_launch(void* const* d_in, const int* in_sizes, int n_in,
                              void* d_out, int out_size, void* d_ws, size_t ws_size,
                              hipStream_t stream) {
  const float* x  = (const float*)d_in[0];
  const float* Wq = (const float*)d_in[1];
  const float* bq = (const float*)d_in[2];
  const float* Wk = (const float*)d_in[3];
  const float* bk = (const float*)d_in[4];
  const float* Wv = (const float*)d_in[5];
  const float* bv = (const float*)d_in[6];
  const float* Wo = (const float*)d_in[7];
  const float* bo = (const float*)d_in[8];
  float* out = (float*)d_out;
  float* ws = (float*)d_ws;

  float* q  = ws + Q_OFF;
  float* t  = ws + T_OFF;
  float* c  = ws + C_OFF;
  float* sc = ws + SC_OFF;
  float* y  = ws + Y_OFF;
  float* op = ws + OP_OFF;

  hipMemsetAsync(y, 0, (size_t)B_ * NH_ * H_ * sizeof(float), stream);
  k_q<<<dim3(4, B_), 256, 0, stream>>>(x, Wq, bq, q);
  k_t<<<dim3(NH_, B_), 256, 0, stream>>>(q, Wk, bk, t, c);
  k_scores<<<dim3(S_ / 256, B_), 256, 0, stream>>>(x, t, c, sc);
  k_softmax<<<dim3(NH_, B_), 256, 0, stream>>>(sc);
  k_y<<<dim3(8, 4, B_), 256, 0, stream>>>(x, sc, y);
  k_vproj<<<dim3(NH_, B_), 256, 0, stream>>>(y, Wv, bv, op);
  k_out<<<dim3(4, B_), 256, 0, stream>>>(op, Wo, bo, out);
}

// Round 2
// 664.696 us; speedup vs baseline: 1.1539x; 1.1539x over previous
//
#include <hip/hip_runtime.h>
#include <hip/hip_bf16.h>

#define B_  32
#define S_  4096
#define H_  1024
#define NH_ 16
#define DK_ 64

// workspace layout (float offsets)
#define Q_OFF  0
#define T_OFF  (Q_OFF + B_*H_)            // q: B*H
#define C_OFF  (T_OFF + B_*NH_*H_)        // t: B*NH*H
#define SC_OFF (C_OFF + B_*NH_)           // c: B*NH
#define Y_OFF  (SC_OFF + B_*NH_*S_)       // scores/attn: B*NH*S
#define OP_OFF (Y_OFF + B_*NH_*H_)        // y: B*NH*H

#define DOT4(a, v) ((a).x*(v).x + (a).y*(v).y + (a).z*(v).z + (a).w*(v).w)

// ---------------- kernel 1: q[b,i] = x[b,S-1,:] . Wq[i,:] + bq[i] ----------
// b-grouped: one block computes a 256-wide i-slab for 4 batches -> Wq read 8x not 32x.
__global__ __launch_bounds__(256) void k_q(const float* __restrict__ x,
                                           const float* __restrict__ Wq,
                                           const float* __restrict__ bq,
                                           float* __restrict__ q) {
  __shared__ __align__(16) float xl[4 * H_];
  int islab = blockIdx.x, bg = blockIdx.y, tid = threadIdx.x;
  #pragma unroll
  for (int k = 0; k < 4; ++k) {
    int idx4 = k * 256 + tid;
    int bl = idx4 >> 8, col4 = idx4 & 255;
    *(float4*)&xl[bl * H_ + col4 * 4] =
        *(const float4*)(x + (((size_t)(bg * 4 + bl)) * S_ + (S_ - 1)) * H_ + col4 * 4);
  }
  __syncthreads();
  int i = islab * 256 + tid;
  const float* w = Wq + (size_t)i * H_;
  float acc[4] = {0.f, 0.f, 0.f, 0.f};
  for (int j = 0; j < H_; j += 4) {
    float4 wv = *(const float4*)&w[j];
    #pragma unroll
    for (int bl = 0; bl < 4; ++bl) {
      float4 xv = *(const float4*)&xl[bl * H_ + j];
      acc[bl] += DOT4(xv, wv);
    }
  }
  float bias = bq[i];
  #pragma unroll
  for (int bl = 0; bl < 4; ++bl)
    q[(size_t)(bg * 4 + bl) * H_ + i] = acc[bl] + bias;
}

// -------- kernel 2: t[b,h,j] = sum_d q[b,h,d]*Wk[h*64+d, j]; c[b,h]=q.bk ---
// b-grouped over ALL 32 batches: Wk read exactly once.
__global__ __launch_bounds__(256) void k_t(const float* __restrict__ q,
                                           const float* __restrict__ Wk,
                                           const float* __restrict__ bk,
                                           float* __restrict__ t,
                                           float* __restrict__ c) {
  __shared__ __align__(16) float qh[B_ * DK_];   // 8 KB
  __shared__ __align__(16) float bkh[DK_];
  int js = blockIdx.x, h = blockIdx.y, tid = threadIdx.x;
  #pragma unroll
  for (int k = 0; k < 2; ++k) {
    int idx4 = k * 256 + tid;
    int bl = idx4 >> 4, d4 = idx4 & 15;
    *(float4*)&qh[bl * DK_ + d4 * 4] =
        *(const float4*)(q + (size_t)bl * H_ + h * DK_ + d4 * 4);
  }
  if (tid < 16)
    *(float4*)&bkh[tid * 4] = *(const float4*)(bk + h * DK_ + tid * 4);
  __syncthreads();

  if (js == 0 && tid < B_) {
    float cc = 0.f;
    for (int d = 0; d < DK_; ++d) cc += qh[tid * DK_ + d] * bkh[d];
    c[tid * NH_ + h] = cc;
  }

  int j = js * 256 + tid;
  float acc[B_];
  #pragma unroll
  for (int bl = 0; bl < B_; ++bl) acc[bl] = 0.f;
  for (int d = 0; d < DK_; ++d) {
    float wv = Wk[((size_t)(h * DK_ + d)) * H_ + j];
    #pragma unroll
    for (int bl = 0; bl < B_; ++bl) acc[bl] += qh[bl * DK_ + d] * wv;
  }
  #pragma unroll
  for (int bl = 0; bl < B_; ++bl)
    t[((size_t)(bl * NH_ + h)) * H_ + j] = acc[bl];
}

// --------- kernel 3: scores[b,h,s] = (t[b,h,:].x[b,s,:] + c[b,h])*scale ----
// 1 wave per block, 128 rows. x kept entirely in registers (ping-pong
// prefetch of 16-col chunks); t streamed through a 1KB LDS slice (broadcast
// reads); quad shfl_xor reduce; coalesced score writes via 8KB LDS tile.
__global__ __launch_bounds__(64) void k_scores(const float* __restrict__ x,
                                               const float* __restrict__ t,
                                               const float* __restrict__ c,
                                               float* __restrict__ scores) {
  __shared__ __align__(16) float tl[NH_ * 16];      // [h][16 cols] chunk slice
  __shared__ __align__(16) float scl[NH_ * 128];    // [h][row] output tile

  int b = blockIdx.y, rb = blockIdx.x, tid = threadIdx.x;
  int r = tid >> 2, g = tid & 3;
  int th = tid >> 2, tslot = tid & 3;               // t-staging role
  const float* xg = x + ((size_t)b * S_ + (size_t)rb * 128) * H_;
  const float* tbase = t + (size_t)b * NH_ * H_;

  float acc[8][NH_];
  #pragma unroll
  for (int rr = 0; rr < 8; ++rr)
    #pragma unroll
    for (int h = 0; h < NH_; ++h) acc[rr][h] = 0.f;

  float4 xv[8], px[8], pt;

  // prologue: chunk 0 into xv + tl
  #pragma unroll
  for (int k = 0; k < 8; ++k)
    xv[k] = *(const float4*)(xg + (size_t)(r + 16 * k) * H_ + g * 4);
  pt = *(const float4*)(tbase + (size_t)th * H_ + tslot * 4);
  *(float4*)&tl[th * 16 + tslot * 4] = pt;

#define PREFETCH(dst, cn)                                                     \
  {                                                                           \
    _Pragma("unroll") for (int k = 0; k < 8; ++k)                             \
        dst[k] = *(const float4*)(xg + (size_t)(r + 16 * k) * H_ +            \
                                  (cn) * 16 + g * 4);                         \
    pt = *(const float4*)(tbase + (size_t)th * H_ + (cn) * 16 + tslot * 4);   \
  }
#define COMPUTE(src)                                                          \
  {                                                                           \
    _Pragma("unroll") for (int h = 0; h < NH_; ++h) {                         \
      float4 tv = *(const float4*)&tl[h * 16 + g * 4];                        \
      _Pragma("unroll") for (int rr = 0; rr < 8; ++rr)                        \
          acc[rr][h] += DOT4(src[rr], tv);                                    \
    }                                                                         \
  }

  #pragma unroll 1
  for (int jc2 = 0; jc2 < 32; ++jc2) {
    int c1 = 2 * jc2 + 1;
    int c2 = (2 * jc2 + 2 < 64) ? 2 * jc2 + 2 : 63;
    PREFETCH(px, c1);
    COMPUTE(xv);                          // chunk 2*jc2 (tl holds it)
    *(float4*)&tl[th * 16 + tslot * 4] = pt;   // tl := c1
    PREFETCH(xv, c2);
    COMPUTE(px);                          // chunk c1
    *(float4*)&tl[th * 16 + tslot * 4] = pt;   // tl := c2
  }
#undef PREFETCH
#undef COMPUTE

  // quad reduce over g (cols)
  #pragma unroll
  for (int rr = 0; rr < 8; ++rr)
    #pragma unroll
    for (int h = 0; h < NH_; ++h) {
      float a = acc[rr][h];
      a += __shfl_xor(a, 1);
      a += __shfl_xor(a, 2);
      acc[rr][h] = a;
    }

  // lane (r,g) writes h in [4g,4g+4) for its 8 rows into the LDS tile
  float cv[4];
  #pragma unroll
  for (int hh = 0; hh < 4; ++hh) cv[hh] = c[b * NH_ + g * 4 + hh];
  #pragma unroll
  for (int rr = 0; rr < 8; ++rr)
    #pragma unroll
    for (int hh = 0; hh < 4; ++hh)
      scl[(g * 4 + hh) * 128 + rr * 16 + r] = (acc[rr][g * 4 + hh] + cv[hh]) * 0.125f;
  __syncthreads();

  // coalesced stream-out: 64 threads x 8 float4
  #pragma unroll
  for (int k = 0; k < 8; ++k) {
    int fi = (k * 64 + tid) * 4;
    int h = fi >> 7, row = fi & 127;
    *(float4*)(scores + ((size_t)(b * NH_ + h)) * S_ + rb * 128 + row) =
        *(const float4*)&scl[fi];
  }
}

// ---------------- kernel 4: in-place softmax over S ------------------------
__global__ __launch_bounds__(256) void k_softmax(float* __restrict__ sc) {
  int h = blockIdx.x, b = blockIdx.y, tid = threadIdx.x;
  float* p = sc + ((size_t)(b * NH_ + h)) * S_;
  float4 v[4];
  float m = -3.4e38f;
  #pragma unroll
  for (int k = 0; k < 4; ++k) {
    v[k] = *(const float4*)(p + (size_t)(k * 256 + tid) * 4);
    m = fmaxf(m, fmaxf(fmaxf(v[k].x, v[k].y), fmaxf(v[k].z, v[k].w)));
  }
  __shared__ float redm[4], reds[4];
  #pragma unroll
  for (int o = 32; o; o >>= 1) m = fmaxf(m, __shfl_xor(m, o));
  if ((tid & 63) == 0) redm[tid >> 6] = m;
  __syncthreads();
  m = fmaxf(fmaxf(redm[0], redm[1]), fmaxf(redm[2], redm[3]));
  float s = 0.f;
  #pragma unroll
  for (int k = 0; k < 4; ++k) {
    v[k].x = __expf(v[k].x - m);
    v[k].y = __expf(v[k].y - m);
    v[k].z = __expf(v[k].z - m);
    v[k].w = __expf(v[k].w - m);
    s += v[k].x + v[k].y + v[k].z + v[k].w;
  }
  #pragma unroll
  for (int o = 32; o; o >>= 1) s += __shfl_xor(s, o);
  if ((tid & 63) == 0) reds[tid >> 6] = s;
  __syncthreads();
  s = reds[0] + reds[1] + reds[2] + reds[3];
  float inv = 1.f / s;
  #pragma unroll
  for (int k = 0; k < 4; ++k) {
    v[k].x *= inv; v[k].y *= inv; v[k].z *= inv; v[k].w *= inv;
    *(float4*)(p + (size_t)(k * 256 + tid) * 4) = v[k];
  }
}

// ------------ kernel 5: y[b,h,j] += sum_s attn[b,h,s]*x[b,s,j] -------------
// thread owns a float4 column slice -> 16B/lane fully-coalesced x reads;
// attn addresses are block-uniform -> scalar loads.
__global__ __launch_bounds__(256) void k_y(const float* __restrict__ x,
                                           const float* __restrict__ attn,
                                           float* __restrict__ y) {
  int ch = blockIdx.x;             // 16 chunks of 256 rows
  int b = blockIdx.y;
  int tid = threadIdx.x;
  const float* xp = x + ((size_t)b * S_ + ch * 256) * H_ + tid * 4;
  const float* ap = attn + (size_t)b * NH_ * S_ + ch * 256;
  float acc[NH_][4];
  #pragma unroll
  for (int h = 0; h < NH_; ++h)
    #pragma unroll
    for (int j = 0; j < 4; ++j) acc[h][j] = 0.f;

  for (int ss = 0; ss < 256; ss += 4) {
    float4 xr[4];
    #pragma unroll
    for (int qq = 0; qq < 4; ++qq)
      xr[qq] = *(const float4*)(xp + (size_t)(ss + qq) * H_);
    #pragma unroll
    for (int h = 0; h < NH_; ++h) {
      float4 a4 = *(const float4*)(ap + (size_t)h * S_ + ss);
      acc[h][0] += a4.x * xr[0].x + a4.y * xr[1].x + a4.z * xr[2].x + a4.w * xr[3].x;
      acc[h][1] += a4.x * xr[0].y + a4.y * xr[1].y + a4.z * xr[2].y + a4.w * xr[3].y;
      acc[h][2] += a4.x * xr[0].z + a4.y * xr[1].z + a4.z * xr[2].z + a4.w * xr[3].z;
      acc[h][3] += a4.x * xr[0].w + a4.y * xr[1].w + a4.z * xr[2].w + a4.w * xr[3].w;
    }
  }
  float* yp = y + (size_t)b * NH_ * H_ + tid * 4;
  #pragma unroll
  for (int h = 0; h < NH_; ++h) {
    atomicAdd(yp + (size_t)h * H_ + 0, acc[h][0]);
    atomicAdd(yp + (size_t)h * H_ + 1, acc[h][1]);
    atomicAdd(yp + (size_t)h * H_ + 2, acc[h][2]);
    atomicAdd(yp + (size_t)h * H_ + 3, acc[h][3]);
  }
}

// -------- kernel 6: out_pre[b,h*64+d] = Wv[h*64+d,:].y[b,h,:] + bv ---------
// b-grouped (4 batches/block): Wv read 8x not 32x.
__global__ __launch_bounds__(256) void k_vproj(const float* __restrict__ y,
                                               const float* __restrict__ Wv,
                                               const float* __restrict__ bv,
                                               float* __restrict__ op) {
  __shared__ __align__(16) float yl[4 * H_];
  int h = blockIdx.x, bg = blockIdx.y, tid = threadIdx.x;
  #pragma unroll
  for (int k = 0; k < 4; ++k) {
    int idx4 = k * 256 + tid;
    int bl = idx4 >> 8, col4 = idx4 & 255;
    *(float4*)&yl[bl * H_ + col4 * 4] =
        *(const float4*)(y + ((size_t)((bg * 4 + bl) * NH_ + h)) * H_ + col4 * 4);
  }
  __syncthreads();
  int d = tid >> 2, p = tid & 3;
  const float* w = Wv + ((size_t)(h * DK_ + d)) * H_ + p * 256;
  float acc[4] = {0.f, 0.f, 0.f, 0.f};
  for (int jj = 0; jj < 256; jj += 4) {
    float4 wv = *(const float4*)(w + jj);
    #pragma unroll
    for (int bl = 0; bl < 4; ++bl) {
      float4 yv = *(const float4*)&yl[bl * H_ + p * 256 + jj];
      acc[bl] += DOT4(yv, wv);
    }
  }
  #pragma unroll
  for (int bl = 0; bl < 4; ++bl) {
    acc[bl] += __shfl_xor(acc[bl], 1);
    acc[bl] += __shfl_xor(acc[bl], 2);
  }
  if (p == 0) {
    float bias = bv[h * DK_ + d];
    #pragma unroll
    for (int bl = 0; bl < 4; ++bl)
      op[(size_t)(bg * 4 + bl) * H_ + h * DK_ + d] = acc[bl] + bias;
  }
}

// -------- kernel 7: out[b,i] = Wo[i,:].out_pre[b,:] + bo[i] ----------------
__global__ __launch_bounds__(256) void k_out(const float* __restrict__ op,
                                             const float* __restrict__ Wo,
                                             const float* __restrict__ bo,
                                             float* __restrict__ out) {
  __shared__ __align__(16) float ul[4 * H_];
  int islab = blockIdx.x, bg = blockIdx.y, tid = threadIdx.x;
  #pragma unroll
  for (int k = 0; k < 4; ++k) {
    int idx4 = k * 256 + tid;
    int bl = idx4 >> 8, col4 = idx4 & 255;
    *(float4*)&ul[bl * H_ + col4 * 4] =
        *(const float4*)(op + (size_t)(bg * 4 + bl) * H_ + col4 * 4);
  }
  __syncthreads();
  int i = islab * 256 + tid;
  const float* w = Wo + (size_t)i * H_;
  float acc[4] = {0.f, 0.f, 0.f, 0.f};
  for (int j = 0; j < H_; j += 4) {
    float4 wv = *(const float4*)&w[j];
    #pragma unroll
    for (int bl = 0; bl < 4; ++bl) {
      float4 uv = *(const float4*)&ul[bl * H_ + j];
      acc[bl] += DOT4(uv, wv);
    }
  }
  float bias = bo[i];
  #pragma unroll
  for (int bl = 0; bl < 4; ++bl)
    out[(size_t)(bg * 4 + bl) * H_ + i] = acc[bl] + bias;
}

extern "C" void kernel_launch(void* const* d_in, const int* in_sizes, int n_in,
                              void* d_out, int out_size, void* d_ws, size_t ws_size,
                              hipStream_t stream) {
  const float* x  = (const float*)d_in[0];
  const float* Wq = (const float*)d_in[1];
  const float* bq = (const float*)d_in[2];
  const float* Wk = (const float*)d_in[3];
  const float* bk = (const float*)d_in[4];
  const float* Wv = (const float*)d_in[5];
  const float* bv = (const float*)d_in[6];
  const float* Wo = (const float*)d_in[7];
  const float* bo = (const float*)d_in[8];
  float* out = (float*)d_out;
  float* ws = (float*)d_ws;

  float* q  = ws + Q_OFF;
  float* t  = ws + T_OFF;
  float* c  = ws + C_OFF;
  float* sc = ws + SC_OFF;
  float* y  = ws + Y_OFF;
  float* op = ws + OP_OFF;

  hipMemsetAsync(y, 0, (size_t)B_ * NH_ * H_ * sizeof(float), stream);
  k_q<<<dim3(4, B_ / 4), 256, 0, stream>>>(x, Wq, bq, q);
  k_t<<<dim3(4, NH_), 256, 0, stream>>>(q, Wk, bk, t, c);
  k_scores<<<dim3(S_ / 128, B_), 64, 0, stream>>>(x, t, c, sc);
  k_softmax<<<dim3(NH_, B_), 256, 0, stream>>>(sc);
  k_y<<<dim3(16, B_), 256, 0, stream>>>(x, sc, y);
  k_vproj<<<dim3(NH_, B_ / 4), 256, 0, stream>>>(y, Wv, bv, op);
  k_out<<<dim3(4, B_ / 4), 256, 0, stream>>>(op, Wo, bo, out);
}

// Round 3
// 598.742 us; speedup vs baseline: 1.2811x; 1.1102x over previous
//
#include <hip/hip_runtime.h>
#include <hip/hip_bf16.h>

#define B_  32
#define S_  4096
#define H_  1024
#define NH_ 16
#define DK_ 64

// workspace layout (float offsets)
#define Q_OFF  0
#define T_OFF  (Q_OFF + B_*H_)            // q: B*H
#define C_OFF  (T_OFF + B_*NH_*H_)        // t: B*NH*H
#define SC_OFF (C_OFF + B_*NH_)           // c: B*NH
#define Y_OFF  (SC_OFF + B_*NH_*S_)       // scores/attn: B*NH*S
#define OP_OFF (Y_OFF + B_*NH_*H_)        // y: B*NH*H

#define DOT4(a, v) ((a).x*(v).x + (a).y*(v).y + (a).z*(v).z + (a).w*(v).w)

// ---------------- kernel 1: q[b,i] = x[b,S-1,:] . Wq[i,:] + bq[i] ----------
__global__ __launch_bounds__(256) void k_q(const float* __restrict__ x,
                                           const float* __restrict__ Wq,
                                           const float* __restrict__ bq,
                                           float* __restrict__ q) {
  __shared__ __align__(16) float xl[4 * H_];
  int islab = blockIdx.x, bg = blockIdx.y, tid = threadIdx.x;
  #pragma unroll
  for (int k = 0; k < 4; ++k) {
    int idx4 = k * 256 + tid;
    int bl = idx4 >> 8, col4 = idx4 & 255;
    *(float4*)&xl[bl * H_ + col4 * 4] =
        *(const float4*)(x + (((size_t)(bg * 4 + bl)) * S_ + (S_ - 1)) * H_ + col4 * 4);
  }
  __syncthreads();
  int i = islab * 256 + tid;
  const float* w = Wq + (size_t)i * H_;
  float acc[4] = {0.f, 0.f, 0.f, 0.f};
  for (int j = 0; j < H_; j += 4) {
    float4 wv = *(const float4*)&w[j];
    #pragma unroll
    for (int bl = 0; bl < 4; ++bl) {
      float4 xv = *(const float4*)&xl[bl * H_ + j];
      acc[bl] += DOT4(xv, wv);
    }
  }
  float bias = bq[i];
  #pragma unroll
  for (int bl = 0; bl < 4; ++bl)
    q[(size_t)(bg * 4 + bl) * H_ + i] = acc[bl] + bias;
}

// -------- kernel 2: t[b,h,j] = sum_d q[b,h,d]*Wk[h*64+d, j]; c[b,h]=q.bk ---
__global__ __launch_bounds__(256) void k_t(const float* __restrict__ q,
                                           const float* __restrict__ Wk,
                                           const float* __restrict__ bk,
                                           float* __restrict__ t,
                                           float* __restrict__ c) {
  __shared__ __align__(16) float qh[B_ * DK_];   // 8 KB
  __shared__ __align__(16) float bkh[DK_];
  int js = blockIdx.x, h = blockIdx.y, tid = threadIdx.x;
  #pragma unroll
  for (int k = 0; k < 2; ++k) {
    int idx4 = k * 256 + tid;
    int bl = idx4 >> 4, d4 = idx4 & 15;
    *(float4*)&qh[bl * DK_ + d4 * 4] =
        *(const float4*)(q + (size_t)bl * H_ + h * DK_ + d4 * 4);
  }
  if (tid < 16)
    *(float4*)&bkh[tid * 4] = *(const float4*)(bk + h * DK_ + tid * 4);
  __syncthreads();

  if (js == 0 && tid < B_) {
    float cc = 0.f;
    for (int d = 0; d < DK_; ++d) cc += qh[tid * DK_ + d] * bkh[d];
    c[tid * NH_ + h] = cc;
  }

  int j = js * 256 + tid;
  float acc[B_];
  #pragma unroll
  for (int bl = 0; bl < B_; ++bl) acc[bl] = 0.f;
  for (int d = 0; d < DK_; ++d) {
    float wv = Wk[((size_t)(h * DK_ + d)) * H_ + j];
    #pragma unroll
    for (int bl = 0; bl < B_; ++bl) acc[bl] += qh[bl * DK_ + d] * wv;
  }
  #pragma unroll
  for (int bl = 0; bl < B_; ++bl)
    t[((size_t)(bl * NH_ + h)) * H_ + j] = acc[bl];
}

// --------- kernel 3: scores[b,h,s] = (t[b,h,:].x[b,s,:] + c[b,h])*scale ----
// 1 wave, 64 rows/block, 4 rows/lane (acc = 64 VGPR, no spill).
// x in registers (ping-pong 16-col chunks); t via wave-synchronous 1KB LDS
// slice; quad shfl reduce; direct 64B-segment global writes.
__global__ __launch_bounds__(64) void k_scores(const float* __restrict__ x,
                                               const float* __restrict__ t,
                                               const float* __restrict__ c,
                                               float* __restrict__ scores) {
  __shared__ __align__(16) float tl[NH_ * 16];      // [h][16 cols] chunk slice

  int b = blockIdx.y, rb = blockIdx.x, tid = threadIdx.x;
  int r = tid >> 2, g = tid & 3;                    // row-in-16, col-quarter
  int th = tid >> 2, ts = tid & 3;                  // t-staging role
  const float* xg = x + ((size_t)b * S_ + (size_t)rb * 64) * H_;
  const float* tbase = t + (size_t)b * NH_ * H_;

  float acc[4][NH_];
  #pragma unroll
  for (int rr = 0; rr < 4; ++rr)
    #pragma unroll
    for (int h = 0; h < NH_; ++h) acc[rr][h] = 0.f;

  float4 xv[4], px[4], pt;

  // prologue: chunk 0 into xv + tl
  #pragma unroll
  for (int k = 0; k < 4; ++k)
    xv[k] = *(const float4*)(xg + (size_t)(r + 16 * k) * H_ + g * 4);
  pt = *(const float4*)(tbase + (size_t)th * H_ + ts * 4);
  *(float4*)&tl[th * 16 + ts * 4] = pt;
  __builtin_amdgcn_wave_barrier();

#define PREFETCH(dst, cn)                                                     \
  {                                                                           \
    _Pragma("unroll") for (int k = 0; k < 4; ++k)                             \
        dst[k] = *(const float4*)(xg + (size_t)(r + 16 * k) * H_ +            \
                                  (cn) * 16 + g * 4);                         \
    pt = *(const float4*)(tbase + (size_t)th * H_ + (cn) * 16 + ts * 4);      \
  }
#define COMPUTE(src)                                                          \
  {                                                                           \
    _Pragma("unroll") for (int h = 0; h < NH_; ++h) {                         \
      float4 tv = *(const float4*)&tl[h * 16 + g * 4];                        \
      _Pragma("unroll") for (int rr = 0; rr < 4; ++rr)                        \
          acc[rr][h] += DOT4(src[rr], tv);                                    \
    }                                                                         \
  }

  #pragma unroll 1
  for (int jc2 = 0; jc2 < 32; ++jc2) {
    int c1 = 2 * jc2 + 1;
    int c2 = (2 * jc2 + 2 < 64) ? 2 * jc2 + 2 : 63;
    PREFETCH(px, c1);
    COMPUTE(xv);                               // chunk 2*jc2 (tl holds it)
    __builtin_amdgcn_wave_barrier();
    *(float4*)&tl[th * 16 + ts * 4] = pt;      // tl := c1 (DS in-order/wave)
    __builtin_amdgcn_wave_barrier();
    PREFETCH(xv, c2);
    COMPUTE(px);                               // chunk c1
    __builtin_amdgcn_wave_barrier();
    *(float4*)&tl[th * 16 + ts * 4] = pt;      // tl := c2
    __builtin_amdgcn_wave_barrier();
  }
#undef PREFETCH
#undef COMPUTE

  // quad reduce over g (col quarters)
  #pragma unroll
  for (int rr = 0; rr < 4; ++rr)
    #pragma unroll
    for (int h = 0; h < NH_; ++h) {
      float a = acc[rr][h];
      a += __shfl_xor(a, 1);
      a += __shfl_xor(a, 2);
      acc[rr][h] = a;
    }

  // lane (r,g) writes heads 4g..4g+3 for its 4 rows: 64B segment per quad
  float cv[4];
  #pragma unroll
  for (int hh = 0; hh < 4; ++hh) cv[hh] = c[b * NH_ + g * 4 + hh];
  #pragma unroll
  for (int rr = 0; rr < 4; ++rr)
    #pragma unroll
    for (int hh = 0; hh < 4; ++hh)
      scores[((size_t)(b * NH_ + g * 4 + hh)) * S_ + rb * 64 + rr * 16 + r] =
          (acc[rr][g * 4 + hh] + cv[hh]) * 0.125f;
}

// ---------------- kernel 4: in-place softmax over S ------------------------
__global__ __launch_bounds__(256) void k_softmax(float* __restrict__ sc) {
  int h = blockIdx.x, b = blockIdx.y, tid = threadIdx.x;
  float* p = sc + ((size_t)(b * NH_ + h)) * S_;
  float4 v[4];
  float m = -3.4e38f;
  #pragma unroll
  for (int k = 0; k < 4; ++k) {
    v[k] = *(const float4*)(p + (size_t)(k * 256 + tid) * 4);
    m = fmaxf(m, fmaxf(fmaxf(v[k].x, v[k].y), fmaxf(v[k].z, v[k].w)));
  }
  __shared__ float redm[4], reds[4];
  #pragma unroll
  for (int o = 32; o; o >>= 1) m = fmaxf(m, __shfl_xor(m, o));
  if ((tid & 63) == 0) redm[tid >> 6] = m;
  __syncthreads();
  m = fmaxf(fmaxf(redm[0], redm[1]), fmaxf(redm[2], redm[3]));
  float s = 0.f;
  #pragma unroll
  for (int k = 0; k < 4; ++k) {
    v[k].x = __expf(v[k].x - m);
    v[k].y = __expf(v[k].y - m);
    v[k].z = __expf(v[k].z - m);
    v[k].w = __expf(v[k].w - m);
    s += v[k].x + v[k].y + v[k].z + v[k].w;
  }
  #pragma unroll
  for (int o = 32; o; o >>= 1) s += __shfl_xor(s, o);
  if ((tid & 63) == 0) reds[tid >> 6] = s;
  __syncthreads();
  s = reds[0] + reds[1] + reds[2] + reds[3];
  float inv = 1.f / s;
  #pragma unroll
  for (int k = 0; k < 4; ++k) {
    v[k].x *= inv; v[k].y *= inv; v[k].z *= inv; v[k].w *= inv;
    *(float4*)(p + (size_t)(k * 256 + tid) * 4) = v[k];
  }
}

// ------------ kernel 5: y[b,h,j] += sum_s attn[b,h,s]*x[b,s,j] -------------
__global__ __launch_bounds__(256) void k_y(const float* __restrict__ x,
                                           const float* __restrict__ attn,
                                           float* __restrict__ y) {
  int ch = blockIdx.x;             // 32 chunks of 128 rows
  int b = blockIdx.y;
  int tid = threadIdx.x;
  const float* xp = x + ((size_t)b * S_ + ch * 128) * H_ + tid * 4;
  const float* ap = attn + (size_t)b * NH_ * S_ + ch * 128;
  float acc[NH_][4];
  #pragma unroll
  for (int h = 0; h < NH_; ++h)
    #pragma unroll
    for (int j = 0; j < 4; ++j) acc[h][j] = 0.f;

  for (int ss = 0; ss < 128; ss += 4) {
    float4 xr[4];
    #pragma unroll
    for (int qq = 0; qq < 4; ++qq)
      xr[qq] = *(const float4*)(xp + (size_t)(ss + qq) * H_);
    #pragma unroll
    for (int h = 0; h < NH_; ++h) {
      float4 a4 = *(const float4*)(ap + (size_t)h * S_ + ss);
      acc[h][0] += a4.x * xr[0].x + a4.y * xr[1].x + a4.z * xr[2].x + a4.w * xr[3].x;
      acc[h][1] += a4.x * xr[0].y + a4.y * xr[1].y + a4.z * xr[2].y + a4.w * xr[3].y;
      acc[h][2] += a4.x * xr[0].z + a4.y * xr[1].z + a4.z * xr[2].z + a4.w * xr[3].z;
      acc[h][3] += a4.x * xr[0].w + a4.y * xr[1].w + a4.z * xr[2].w + a4.w * xr[3].w;
    }
  }
  float* yp = y + (size_t)b * NH_ * H_ + tid * 4;
  #pragma unroll
  for (int h = 0; h < NH_; ++h) {
    atomicAdd(yp + (size_t)h * H_ + 0, acc[h][0]);
    atomicAdd(yp + (size_t)h * H_ + 1, acc[h][1]);
    atomicAdd(yp + (size_t)h * H_ + 2, acc[h][2]);
    atomicAdd(yp + (size_t)h * H_ + 3, acc[h][3]);
  }
}

// -------- kernel 6: out_pre[b,h*64+d] = Wv[h*64+d,:].y[b,h,:] + bv ---------
__global__ __launch_bounds__(256) void k_vproj(const float* __restrict__ y,
                                               const float* __restrict__ Wv,
                                               const float* __restrict__ bv,
                                               float* __restrict__ op) {
  __shared__ __align__(16) float yl[4 * H_];
  int h = blockIdx.x, bg = blockIdx.y, tid = threadIdx.x;
  #pragma unroll
  for (int k = 0; k < 4; ++k) {
    int idx4 = k * 256 + tid;
    int bl = idx4 >> 8, col4 = idx4 & 255;
    *(float4*)&yl[bl * H_ + col4 * 4] =
        *(const float4*)(y + ((size_t)((bg * 4 + bl) * NH_ + h)) * H_ + col4 * 4);
  }
  __syncthreads();
  int d = tid >> 2, p = tid & 3;
  const float* w = Wv + ((size_t)(h * DK_ + d)) * H_ + p * 256;
  float acc[4] = {0.f, 0.f, 0.f, 0.f};
  for (int jj = 0; jj < 256; jj += 4) {
    float4 wv = *(const float4*)(w + jj);
    #pragma unroll
    for (int bl = 0; bl < 4; ++bl) {
      float4 yv = *(const float4*)&yl[bl * H_ + p * 256 + jj];
      acc[bl] += DOT4(yv, wv);
    }
  }
  #pragma unroll
  for (int bl = 0; bl < 4; ++bl) {
    acc[bl] += __shfl_xor(acc[bl], 1);
    acc[bl] += __shfl_xor(acc[bl], 2);
  }
  if (p == 0) {
    float bias = bv[h * DK_ + d];
    #pragma unroll
    for (int bl = 0; bl < 4; ++bl)
      op[(size_t)(bg * 4 + bl) * H_ + h * DK_ + d] = acc[bl] + bias;
  }
}

// -------- kernel 7: out[b,i] = Wo[i,:].out_pre[b,:] + bo[i] ----------------
__global__ __launch_bounds__(256) void k_out(const float* __restrict__ op,
                                             const float* __restrict__ Wo,
                                             const float* __restrict__ bo,
                                             float* __restrict__ out) {
  __shared__ __align__(16) float ul[4 * H_];
  int islab = blockIdx.x, bg = blockIdx.y, tid = threadIdx.x;
  #pragma unroll
  for (int k = 0; k < 4; ++k) {
    int idx4 = k * 256 + tid;
    int bl = idx4 >> 8, col4 = idx4 & 255;
    *(float4*)&ul[bl * H_ + col4 * 4] =
        *(const float4*)(op + (size_t)(bg * 4 + bl) * H_ + col4 * 4);
  }
  __syncthreads();
  int i = islab * 256 + tid;
  const float* w = Wo + (size_t)i * H_;
  float acc[4] = {0.f, 0.f, 0.f, 0.f};
  for (int j = 0; j < H_; j += 4) {
    float4 wv = *(const float4*)&w[j];
    #pragma unroll
    for (int bl = 0; bl < 4; ++bl) {
      float4 uv = *(const float4*)&ul[bl * H_ + j];
      acc[bl] += DOT4(uv, wv);
    }
  }
  float bias = bo[i];
  #pragma unroll
  for (int bl = 0; bl < 4; ++bl)
    out[(size_t)(bg * 4 + bl) * H_ + i] = acc[bl] + bias;
}

extern "C" void kernel_launch(void* const* d_in, const int* in_sizes, int n_in,
                              void* d_out, int out_size, void* d_ws, size_t ws_size,
                              hipStream_t stream) {
  const float* x  = (const float*)d_in[0];
  const float* Wq = (const float*)d_in[1];
  const float* bq = (const float*)d_in[2];
  const float* Wk = (const float*)d_in[3];
  const float* bk = (const float*)d_in[4];
  const float* Wv = (const float*)d_in[5];
  const float* bv = (const float*)d_in[6];
  const float* Wo = (const float*)d_in[7];
  const float* bo = (const float*)d_in[8];
  float* out = (float*)d_out;
  float* ws = (float*)d_ws;

  float* q  = ws + Q_OFF;
  float* t  = ws + T_OFF;
  float* c  = ws + C_OFF;
  float* sc = ws + SC_OFF;
  float* y  = ws + Y_OFF;
  float* op = ws + OP_OFF;

  hipMemsetAsync(y, 0, (size_t)B_ * NH_ * H_ * sizeof(float), stream);
  k_q<<<dim3(4, B_ / 4), 256, 0, stream>>>(x, Wq, bq, q);
  k_t<<<dim3(4, NH_), 256, 0, stream>>>(q, Wk, bk, t, c);
  k_scores<<<dim3(S_ / 64, B_), 64, 0, stream>>>(x, t, c, sc);
  k_softmax<<<dim3(NH_, B_), 256, 0, stream>>>(sc);
  k_y<<<dim3(32, B_), 256, 0, stream>>>(x, sc, y);
  k_vproj<<<dim3(NH_, B_ / 4), 256, 0, stream>>>(y, Wv, bv, op);
  k_out<<<dim3(4, B_ / 4), 256, 0, stream>>>(op, Wo, bo, out);
}

// Round 4
// 467.644 us; speedup vs baseline: 1.6402x; 1.2803x over previous
//
#include <hip/hip_runtime.h>
#include <hip/hip_bf16.h>

#define B_  32
#define S_  4096
#define H_  1024
#define NH_ 16
#define DK_ 64
#define NCH 32                            // k_y chunks (128 rows each)

// workspace layout (float offsets)
#define Q_OFF  0
#define T_OFF  (Q_OFF + B_*H_)            // q: B*H
#define C_OFF  (T_OFF + B_*NH_*H_)        // t: B*NH*H
#define SC_OFF (C_OFF + B_*NH_)           // c: B*NH
#define YP_OFF (SC_OFF + B_*NH_*S_)       // scores/attn: B*NH*S
#define OP_OFF (YP_OFF + NCH*B_*NH_*H_)   // y_part: NCH*B*NH*H (64 MB)

#define DOT4(a, v) ((a).x*(v).x + (a).y*(v).y + (a).z*(v).z + (a).w*(v).w)

// ---------------- kernel 1: q[b,i] = x[b,S-1,:] . Wq[i,:] + bq[i] ----------
__global__ __launch_bounds__(256) void k_q(const float* __restrict__ x,
                                           const float* __restrict__ Wq,
                                           const float* __restrict__ bq,
                                           float* __restrict__ q) {
  __shared__ __align__(16) float xl[4 * H_];
  int islab = blockIdx.x, bg = blockIdx.y, tid = threadIdx.x;
  #pragma unroll
  for (int k = 0; k < 4; ++k) {
    int idx4 = k * 256 + tid;
    int bl = idx4 >> 8, col4 = idx4 & 255;
    *(float4*)&xl[bl * H_ + col4 * 4] =
        *(const float4*)(x + (((size_t)(bg * 4 + bl)) * S_ + (S_ - 1)) * H_ + col4 * 4);
  }
  __syncthreads();
  int i = islab * 256 + tid;
  const float* w = Wq + (size_t)i * H_;
  float acc[4] = {0.f, 0.f, 0.f, 0.f};
  for (int j = 0; j < H_; j += 4) {
    float4 wv = *(const float4*)&w[j];
    #pragma unroll
    for (int bl = 0; bl < 4; ++bl) {
      float4 xv = *(const float4*)&xl[bl * H_ + j];
      acc[bl] += DOT4(xv, wv);
    }
  }
  float bias = bq[i];
  #pragma unroll
  for (int bl = 0; bl < 4; ++bl)
    q[(size_t)(bg * 4 + bl) * H_ + i] = acc[bl] + bias;
}

// -------- kernel 2: t[b,h,j] = sum_d q[b,h,d]*Wk[h*64+d, j]; c[b,h]=q.bk ---
__global__ __launch_bounds__(256) void k_t(const float* __restrict__ q,
                                           const float* __restrict__ Wk,
                                           const float* __restrict__ bk,
                                           float* __restrict__ t,
                                           float* __restrict__ c) {
  __shared__ __align__(16) float qh[B_ * DK_];   // 8 KB
  __shared__ __align__(16) float bkh[DK_];
  int js = blockIdx.x, h = blockIdx.y, tid = threadIdx.x;
  #pragma unroll
  for (int k = 0; k < 2; ++k) {
    int idx4 = k * 256 + tid;
    int bl = idx4 >> 4, d4 = idx4 & 15;
    *(float4*)&qh[bl * DK_ + d4 * 4] =
        *(const float4*)(q + (size_t)bl * H_ + h * DK_ + d4 * 4);
  }
  if (tid < 16)
    *(float4*)&bkh[tid * 4] = *(const float4*)(bk + h * DK_ + tid * 4);
  __syncthreads();

  if (js == 0 && tid < B_) {
    float cc = 0.f;
    for (int d = 0; d < DK_; ++d) cc += qh[tid * DK_ + d] * bkh[d];
    c[tid * NH_ + h] = cc;
  }

  int j = js * 256 + tid;
  float acc[B_];
  #pragma unroll
  for (int bl = 0; bl < B_; ++bl) acc[bl] = 0.f;
  for (int d = 0; d < DK_; ++d) {
    float wv = Wk[((size_t)(h * DK_ + d)) * H_ + j];
    #pragma unroll
    for (int bl = 0; bl < B_; ++bl) acc[bl] += qh[bl * DK_ + d] * wv;
  }
  #pragma unroll
  for (int bl = 0; bl < B_; ++bl)
    t[((size_t)(bl * NH_ + h)) * H_ + j] = acc[bl];
}

// --------- kernel 3: scores[b,h,s] = (t[b,h,:].x[b,s,:] + c[b,h])*scale ----
// 1 wave, 64 rows/block, 4 rows/lane. x in registers (ping-pong 16-col
// chunks); t via wave-synchronous 1KB LDS slice; quad shfl reduce;
// 64B-segment global writes.
__global__ __launch_bounds__(64) void k_scores(const float* __restrict__ x,
                                               const float* __restrict__ t,
                                               const float* __restrict__ c,
                                               float* __restrict__ scores) {
  __shared__ __align__(16) float tl[NH_ * 16];      // [h][16 cols] chunk slice

  int b = blockIdx.y, rb = blockIdx.x, tid = threadIdx.x;
  int r = tid >> 2, g = tid & 3;                    // row-in-16, col-quarter
  int th = tid >> 2, ts = tid & 3;                  // t-staging role
  const float* xg = x + ((size_t)b * S_ + (size_t)rb * 64) * H_;
  const float* tbase = t + (size_t)b * NH_ * H_;

  float acc[4][NH_];
  #pragma unroll
  for (int rr = 0; rr < 4; ++rr)
    #pragma unroll
    for (int h = 0; h < NH_; ++h) acc[rr][h] = 0.f;

  float4 xv[4], px[4], pt;

  // prologue: chunk 0 into xv + tl
  #pragma unroll
  for (int k = 0; k < 4; ++k)
    xv[k] = *(const float4*)(xg + (size_t)(r + 16 * k) * H_ + g * 4);
  pt = *(const float4*)(tbase + (size_t)th * H_ + ts * 4);
  *(float4*)&tl[th * 16 + ts * 4] = pt;
  __builtin_amdgcn_wave_barrier();

#define PREFETCH(dst, cn)                                                     \
  {                                                                           \
    _Pragma("unroll") for (int k = 0; k < 4; ++k)                             \
        dst[k] = *(const float4*)(xg + (size_t)(r + 16 * k) * H_ +            \
                                  (cn) * 16 + g * 4);                         \
    pt = *(const float4*)(tbase + (size_t)th * H_ + (cn) * 16 + ts * 4);      \
  }
#define COMPUTE(src)                                                          \
  {                                                                           \
    _Pragma("unroll") for (int h = 0; h < NH_; ++h) {                         \
      float4 tv = *(const float4*)&tl[h * 16 + g * 4];                        \
      _Pragma("unroll") for (int rr = 0; rr < 4; ++rr)                        \
          acc[rr][h] += DOT4(src[rr], tv);                                    \
    }                                                                         \
  }

  #pragma unroll 1
  for (int jc2 = 0; jc2 < 32; ++jc2) {
    int c1 = 2 * jc2 + 1;
    int c2 = (2 * jc2 + 2 < 64) ? 2 * jc2 + 2 : 63;
    PREFETCH(px, c1);
    COMPUTE(xv);                               // chunk 2*jc2 (tl holds it)
    __builtin_amdgcn_wave_barrier();
    *(float4*)&tl[th * 16 + ts * 4] = pt;      // tl := c1 (DS in-order/wave)
    __builtin_amdgcn_wave_barrier();
    PREFETCH(xv, c2);
    COMPUTE(px);                               // chunk c1
    __builtin_amdgcn_wave_barrier();
    *(float4*)&tl[th * 16 + ts * 4] = pt;      // tl := c2
    __builtin_amdgcn_wave_barrier();
  }
#undef PREFETCH
#undef COMPUTE

  // quad reduce over g (col quarters)
  #pragma unroll
  for (int rr = 0; rr < 4; ++rr)
    #pragma unroll
    for (int h = 0; h < NH_; ++h) {
      float a = acc[rr][h];
      a += __shfl_xor(a, 1);
      a += __shfl_xor(a, 2);
      acc[rr][h] = a;
    }

  // lane (r,g) writes heads 4g..4g+3 for its 4 rows: 64B segment per quad
  float cv[4];
  #pragma unroll
  for (int hh = 0; hh < 4; ++hh) cv[hh] = c[b * NH_ + g * 4 + hh];
  #pragma unroll
  for (int rr = 0; rr < 4; ++rr)
    #pragma unroll
    for (int hh = 0; hh < 4; ++hh)
      scores[((size_t)(b * NH_ + g * 4 + hh)) * S_ + rb * 64 + rr * 16 + r] =
          (acc[rr][g * 4 + hh] + cv[hh]) * 0.125f;
}

// ---------------- kernel 4: in-place softmax over S ------------------------
__global__ __launch_bounds__(256) void k_softmax(float* __restrict__ sc) {
  int h = blockIdx.x, b = blockIdx.y, tid = threadIdx.x;
  float* p = sc + ((size_t)(b * NH_ + h)) * S_;
  float4 v[4];
  float m = -3.4e38f;
  #pragma unroll
  for (int k = 0; k < 4; ++k) {
    v[k] = *(const float4*)(p + (size_t)(k * 256 + tid) * 4);
    m = fmaxf(m, fmaxf(fmaxf(v[k].x, v[k].y), fmaxf(v[k].z, v[k].w)));
  }
  __shared__ float redm[4], reds[4];
  #pragma unroll
  for (int o = 32; o; o >>= 1) m = fmaxf(m, __shfl_xor(m, o));
  if ((tid & 63) == 0) redm[tid >> 6] = m;
  __syncthreads();
  m = fmaxf(fmaxf(redm[0], redm[1]), fmaxf(redm[2], redm[3]));
  float s = 0.f;
  #pragma unroll
  for (int k = 0; k < 4; ++k) {
    v[k].x = __expf(v[k].x - m);
    v[k].y = __expf(v[k].y - m);
    v[k].z = __expf(v[k].z - m);
    v[k].w = __expf(v[k].w - m);
    s += v[k].x + v[k].y + v[k].z + v[k].w;
  }
  #pragma unroll
  for (int o = 32; o; o >>= 1) s += __shfl_xor(s, o);
  if ((tid & 63) == 0) reds[tid >> 6] = s;
  __syncthreads();
  s = reds[0] + reds[1] + reds[2] + reds[3];
  float inv = 1.f / s;
  #pragma unroll
  for (int k = 0; k < 4; ++k) {
    v[k].x *= inv; v[k].y *= inv; v[k].z *= inv; v[k].w *= inv;
    *(float4*)(p + (size_t)(k * 256 + tid) * 4) = v[k];
  }
}

// ---- kernel 5: y_part[ch,b,h,j] = sum_{s in chunk} attn[b,h,s]*x[b,s,j] ---
// Plain coalesced stores (no atomics, no zero-init needed).
__global__ __launch_bounds__(256) void k_y(const float* __restrict__ x,
                                           const float* __restrict__ attn,
                                           float* __restrict__ ypart) {
  int ch = blockIdx.x;             // NCH chunks of 128 rows
  int b = blockIdx.y;
  int tid = threadIdx.x;
  const float* xp = x + ((size_t)b * S_ + ch * 128) * H_ + tid * 4;
  const float* ap = attn + (size_t)b * NH_ * S_ + ch * 128;
  float acc[NH_][4];
  #pragma unroll
  for (int h = 0; h < NH_; ++h)
    #pragma unroll
    for (int j = 0; j < 4; ++j) acc[h][j] = 0.f;

  for (int ss = 0; ss < 128; ss += 4) {
    float4 xr[4];
    #pragma unroll
    for (int qq = 0; qq < 4; ++qq)
      xr[qq] = *(const float4*)(xp + (size_t)(ss + qq) * H_);
    #pragma unroll
    for (int h = 0; h < NH_; ++h) {
      float4 a4 = *(const float4*)(ap + (size_t)h * S_ + ss);
      acc[h][0] += a4.x * xr[0].x + a4.y * xr[1].x + a4.z * xr[2].x + a4.w * xr[3].x;
      acc[h][1] += a4.x * xr[0].y + a4.y * xr[1].y + a4.z * xr[2].y + a4.w * xr[3].y;
      acc[h][2] += a4.x * xr[0].z + a4.y * xr[1].z + a4.z * xr[2].z + a4.w * xr[3].z;
      acc[h][3] += a4.x * xr[0].w + a4.y * xr[1].w + a4.z * xr[2].w + a4.w * xr[3].w;
    }
  }
  float* yp = ypart + ((size_t)ch * B_ + b) * NH_ * H_ + tid * 4;
  #pragma unroll
  for (int h = 0; h < NH_; ++h) {
    float4 v;
    v.x = acc[h][0]; v.y = acc[h][1]; v.z = acc[h][2]; v.w = acc[h][3];
    *(float4*)(yp + (size_t)h * H_) = v;
  }
}

// -- kernel 6: op[b,h*64+d] = Wv[h*64+d,:].(sum_ch y_part[ch,b,h,:]) + bv ---
__global__ __launch_bounds__(256) void k_vproj(const float* __restrict__ ypart,
                                               const float* __restrict__ Wv,
                                               const float* __restrict__ bv,
                                               float* __restrict__ op) {
  __shared__ __align__(16) float yl[4 * H_];
  int h = blockIdx.x, bg = blockIdx.y, tid = threadIdx.x;
  float4 acc4[4];
  #pragma unroll
  for (int bl = 0; bl < 4; ++bl) { acc4[bl].x = acc4[bl].y = acc4[bl].z = acc4[bl].w = 0.f; }
  for (int ch = 0; ch < NCH; ++ch) {
    #pragma unroll
    for (int bl = 0; bl < 4; ++bl) {
      float4 v = *(const float4*)(ypart +
          ((size_t)ch * B_ + bg * 4 + bl) * NH_ * H_ + (size_t)h * H_ + tid * 4);
      acc4[bl].x += v.x; acc4[bl].y += v.y; acc4[bl].z += v.z; acc4[bl].w += v.w;
    }
  }
  #pragma unroll
  for (int bl = 0; bl < 4; ++bl)
    *(float4*)&yl[bl * H_ + tid * 4] = acc4[bl];
  __syncthreads();

  int d = tid >> 2, p = tid & 3;
  const float* w = Wv + ((size_t)(h * DK_ + d)) * H_ + p * 256;
  float acc[4] = {0.f, 0.f, 0.f, 0.f};
  for (int jj = 0; jj < 256; jj += 4) {
    float4 wv = *(const float4*)(w + jj);
    #pragma unroll
    for (int bl = 0; bl < 4; ++bl) {
      float4 yv = *(const float4*)&yl[bl * H_ + p * 256 + jj];
      acc[bl] += DOT4(yv, wv);
    }
  }
  #pragma unroll
  for (int bl = 0; bl < 4; ++bl) {
    acc[bl] += __shfl_xor(acc[bl], 1);
    acc[bl] += __shfl_xor(acc[bl], 2);
  }
  if (p == 0) {
    float bias = bv[h * DK_ + d];
    #pragma unroll
    for (int bl = 0; bl < 4; ++bl)
      op[(size_t)(bg * 4 + bl) * H_ + h * DK_ + d] = acc[bl] + bias;
  }
}

// -------- kernel 7: out[b,i] = Wo[i,:].out_pre[b,:] + bo[i] ----------------
__global__ __launch_bounds__(256) void k_out(const float* __restrict__ op,
                                             const float* __restrict__ Wo,
                                             const float* __restrict__ bo,
                                             float* __restrict__ out) {
  __shared__ __align__(16) float ul[4 * H_];
  int islab = blockIdx.x, bg = blockIdx.y, tid = threadIdx.x;
  #pragma unroll
  for (int k = 0; k < 4; ++k) {
    int idx4 = k * 256 + tid;
    int bl = idx4 >> 8, col4 = idx4 & 255;
    *(float4*)&ul[bl * H_ + col4 * 4] =
        *(const float4*)(op + (size_t)(bg * 4 + bl) * H_ + col4 * 4);
  }
  __syncthreads();
  int i = islab * 256 + tid;
  const float* w = Wo + (size_t)i * H_;
  float acc[4] = {0.f, 0.f, 0.f, 0.f};
  for (int j = 0; j < H_; j += 4) {
    float4 wv = *(const float4*)&w[j];
    #pragma unroll
    for (int bl = 0; bl < 4; ++bl) {
      float4 uv = *(const float4*)&ul[bl * H_ + j];
      acc[bl] += DOT4(uv, wv);
    }
  }
  float bias = bo[i];
  #pragma unroll
  for (int bl = 0; bl < 4; ++bl)
    out[(size_t)(bg * 4 + bl) * H_ + i] = acc[bl] + bias;
}

extern "C" void kernel_launch(void* const* d_in, const int* in_sizes, int n_in,
                              void* d_out, int out_size, void* d_ws, size_t ws_size,
                              hipStream_t stream) {
  const float* x  = (const float*)d_in[0];
  const float* Wq = (const float*)d_in[1];
  const float* bq = (const float*)d_in[2];
  const float* Wk = (const float*)d_in[3];
  const float* bk = (const float*)d_in[4];
  const float* Wv = (const float*)d_in[5];
  const float* bv = (const float*)d_in[6];
  const float* Wo = (const float*)d_in[7];
  const float* bo = (const float*)d_in[8];
  float* out = (float*)d_out;
  float* ws = (float*)d_ws;

  float* q  = ws + Q_OFF;
  float* t  = ws + T_OFF;
  float* c  = ws + C_OFF;
  float* sc = ws + SC_OFF;
  float* yp = ws + YP_OFF;
  float* op = ws + OP_OFF;

  k_q<<<dim3(4, B_ / 4), 256, 0, stream>>>(x, Wq, bq, q);
  k_t<<<dim3(4, NH_), 256, 0, stream>>>(q, Wk, bk, t, c);
  k_scores<<<dim3(S_ / 64, B_), 64, 0, stream>>>(x, t, c, sc);
  k_softmax<<<dim3(NH_, B_), 256, 0, stream>>>(sc);
  k_y<<<dim3(NCH, B_), 256, 0, stream>>>(x, sc, yp);
  k_vproj<<<dim3(NH_, B_ / 4), 256, 0, stream>>>(yp, Wv, bv, op);
  k_out<<<dim3(4, B_ / 4), 256, 0, stream>>>(op, Wo, bo, out);
}